// Round 6
// baseline (96.238 us; speedup 1.0000x reference)
//
#include <hip/hip_runtime.h>
#include <math.h>

#define EPSILON 1e-6f
#define COS_EPS 1e-8f
#define NN 2048
#define FF 128
#define BLK 512     // 8 waves
#define UNROLL 8    // rows in flight per wave = 2*UNROLL

typedef float floatx4 __attribute__((ext_vector_type(4)));  // native vec for nontemporal builtins

__launch_bounds__(BLK, 2)
__global__ void ntm_head_kernel(const float* __restrict__ m,
                                const float* __restrict__ kk,
                                const float* __restrict__ beta_,
                                const float* __restrict__ g_,
                                const float* __restrict__ s_,
                                const float* __restrict__ r_,
                                const float* __restrict__ wp,
                                float* __restrict__ out) {
  const int b    = blockIdx.x;
  const int tid  = threadIdx.x;
  const int wv   = tid >> 6;      // wave id 0..7
  const int lane = tid & 63;
  const int h    = lane >> 5;     // half-wave id 0/1
  const int l32  = lane & 31;

  __shared__ float simbuf[NN];    // exp(beta*sim)
  __shared__ float warr[NN];      // interpolated weights
  __shared__ float red_s[8];      // per-wave softmax partial sums
  __shared__ float red_p[8];      // per-wave sharpen partial sums

  // prefetch w_prev (read-once -> nt), one dwordx4 per thread; latency hides
  // under the content stream
  floatx4 wprv4 = __builtin_nontemporal_load(
      reinterpret_cast<const floatx4*>(wp + (size_t)b * NN + 4 * tid));

  // per-batch scalars
  const float beta = beta_[b];
  const float gg   = g_[b];
  const float s0 = s_[b * 3 + 0], s1 = s_[b * 3 + 1], s2 = s_[b * 3 + 2];
  const float rr = r_[b];

  // key fragment: lane holds k[4*l32 .. 4*l32+3]  (F=128 = 32 lanes * 4)
  float4 kv = *reinterpret_cast<const float4*>(kk + (size_t)b * FF + 4 * l32);
  const float ke0 = kv.x + EPSILON, ke1 = kv.y + EPSILON;
  const float ke2 = kv.z + EPSILON, ke3 = kv.w + EPSILON;
  float ksq = ke0 * ke0 + ke1 * ke1 + ke2 * ke2 + ke3 * ke3;
  #pragma unroll
  for (int off = 1; off < 32; off <<= 1) ksq += __shfl_xor(ksq, off);
  const float inv_knorm = __builtin_amdgcn_rsqf(ksq);   // 1/||k+eps||

  const float* mb = m + (size_t)b * NN * FF;

  // ---- content addressing + fused exp + fused denominator accumulation ----
  // beta*sim in [-5,5] (|cos|<=1, b<5) so exp() is overflow-safe without
  // max subtraction (mathematically identical to softmax).
  float lsum = 0.f;
  for (int it = 0; it < NN / 16; it += UNROLL) {
    floatx4 mv[UNROLL];
    #pragma unroll
    for (int u = 0; u < UNROLL; ++u) {
      int n = (it + u) * 16 + wv * 2 + h;
      // non-temporal: m has zero reuse — skip cache allocation on the stream
      mv[u] = __builtin_nontemporal_load(
          reinterpret_cast<const floatx4*>(mb + (size_t)n * FF + 4 * l32));
    }
    #pragma unroll
    for (int u = 0; u < UNROLL; ++u) {
      int n = (it + u) * 16 + wv * 2 + h;
      float m0 = mv[u].x + EPSILON, m1 = mv[u].y + EPSILON;
      float m2 = mv[u].z + EPSILON, m3 = mv[u].w + EPSILON;
      float dp = m0 * ke0 + m1 * ke1 + m2 * ke2 + m3 * ke3;
      float sq = m0 * m0 + m1 * m1 + m2 * m2 + m3 * m3;
      #pragma unroll
      for (int off = 1; off < 32; off <<= 1) {   // 5 steps, serves both halves
        dp += __shfl_xor(dp, off);
        sq += __shfl_xor(sq, off);
      }
      float a = beta * dp * __builtin_amdgcn_rsqf(sq) * inv_knorm;
      float e = __expf(a);
      if (l32 == 0) simbuf[n] = e;
      lsum += e;
    }
  }
  lsum += __shfl_xor(lsum, 32);      // merge halves -> wave total
  if (lane == 0) red_s[wv] = lsum;
  __syncthreads();                   // #1: simbuf + red_s ready

  float ssum = 0.f;
  #pragma unroll
  for (int i = 0; i < 8; ++i) ssum += red_s[i];
  const float inv_softmax = 1.0f / ssum;   // jax softmax: no epsilon
  const float om_g = 1.0f - gg;

  // ---- interpolation: w = softmax + (1-g)*w_prev ----
  {
    int n0 = 4 * tid;
    warr[n0 + 0] = simbuf[n0 + 0] * inv_softmax + om_g * wprv4.x;
    warr[n0 + 1] = simbuf[n0 + 1] * inv_softmax + om_g * wprv4.y;
    warr[n0 + 2] = simbuf[n0 + 2] * inv_softmax + om_g * wprv4.z;
    warr[n0 + 3] = simbuf[n0 + 3] * inv_softmax + om_g * wprv4.w;
  }
  __syncthreads();                   // #2: warr ready

  // ---- circular shift (3-tap) + sharpen ----
  // thread handles n0..n0+3 (contiguous) so the final store is one dwordx4
  const int n0 = 4 * tid;
  floatx4 pv;
  float lsum2 = 0.f;
  #pragma unroll
  for (int i = 0; i < 4; ++i) {
    int n = n0 + i;
    float prev = warr[(n + NN - 1) & (NN - 1)];
    float cur  = warr[n];
    float nxt  = warr[(n + 1) & (NN - 1)];
    float sh = s0 * prev + s1 * cur + s2 * nxt;   // strictly > 0
    float p = __expf(rr * __logf(sh));            // sh^r
    pv[i] = p;
    lsum2 += p;
  }
  #pragma unroll
  for (int off = 1; off < 64; off <<= 1) lsum2 += __shfl_xor(lsum2, off);
  if (lane == 0) red_p[wv] = lsum2;
  __syncthreads();                   // #3: red_p ready

  float psum = 0.f;
  #pragma unroll
  for (int i = 0; i < 8; ++i) psum += red_p[i];
  const float inv_sharp = 1.0f / (psum + EPSILON);

  pv *= inv_sharp;
  __builtin_nontemporal_store(
      pv, reinterpret_cast<floatx4*>(out + (size_t)b * NN + n0));
}

extern "C" void kernel_launch(void* const* d_in, const int* in_sizes, int n_in,
                              void* d_out, int out_size, void* d_ws, size_t ws_size,
                              hipStream_t stream) {
  const float* m  = (const float*)d_in[0];
  const float* k  = (const float*)d_in[1];
  const float* b  = (const float*)d_in[2];
  const float* g  = (const float*)d_in[3];
  const float* s  = (const float*)d_in[4];
  const float* r  = (const float*)d_in[5];
  const float* wp = (const float*)d_in[6];
  float* out = (float*)d_out;

  ntm_head_kernel<<<dim3(512), dim3(BLK), 0, stream>>>(m, k, b, g, s, r, wp, out);
}